// Round 5
// baseline (221.902 us; speedup 1.0000x reference)
//
#include <hip/hip_runtime.h>
#include <stdint.h>

typedef unsigned short u16;
typedef __bf16 bf16x8 __attribute__((ext_vector_type(8)));
typedef float f32x16 __attribute__((ext_vector_type(16)));
typedef u16 u16x8 __attribute__((ext_vector_type(8)));

__device__ __forceinline__ u16 f2bf(float f) {
  uint32_t u = __float_as_uint(f);
  u += 0x7fffu + ((u >> 16) & 1u);   // round-to-nearest-even
  return (u16)(u >> 16);
}

// ---------------------------------------------------------------------------
// build_lr (R5): R3/R4 version measured ~100 us (by total-minus-parts):
// scalar LDS reads in the contraction loops left a ~120-cyc latency chain
// per element with 1 wave/SIMD and no ILP. R5: explicit float4 LDS reads
// (ds_read_b128), fully unrolled -> 4 independent loads + 16 independent
// FMAs per l-step; compiler can hoist/pipeline. Accumulation order
// unchanged (ascending l; serial adds ascending rk) -> bit-identical f32.
//   blocks 0..63 : L4[AL(128)][BL(128)][r4(16)], thread = (AL,BL)
//   block 64     : R[AR(16)][BR(16)][r(16)], thread = (AR,BR)
// ---------------------------------------------------------------------------
__global__ __launch_bounds__(256) void build_lr_kernel(
    const float* __restrict__ p0, const float* __restrict__ p1,
    const float* __restrict__ p2, const float* __restrict__ p3,
    const float* __restrict__ p4, const float* __restrict__ p5,
    const float* __restrict__ p6, const float* __restrict__ p7,
    const float* __restrict__ p8, float* __restrict__ L4, float* __restrict__ R) {
  __shared__ alignas(16) float sC[5 * 1024];
  const int tid = threadIdx.x;
  if (blockIdx.x < 64) {
    for (int i = tid; i < 1024; i += 256) {
      sC[i]        = p0[i];
      sC[1024 + i] = p1[i];
      sC[2048 + i] = p2[i];
      sC[3072 + i] = p3[i];
      sC[4096 + i] = p4[i];
    }
    __syncthreads();
    const int idx = blockIdx.x * 256 + tid;   // AL*128 + BL
    const int AL = idx >> 7, BL = idx & 127;
    float t[16], u[16];
    {
      const float4* c0 = (const float4*)(sC + ((AL >> 4) * 8 + (BL >> 4)) * 16);
      float4 a = c0[0], b = c0[1], c = c0[2], d = c0[3];
      t[0] = a.x; t[1] = a.y; t[2] = a.z; t[3] = a.w;
      t[4] = b.x; t[5] = b.y; t[6] = b.z; t[7] = b.w;
      t[8] = c.x; t[9] = c.y; t[10] = c.z; t[11] = c.w;
      t[12] = d.x; t[13] = d.y; t[14] = d.z; t[15] = d.w;
    }
#pragma unroll
    for (int k = 0; k < 4; k++) {
      const int ak = (AL >> (3 - k)) & 1;
      const int bk = (BL >> (3 - k)) & 1;
      const float* ck = sC + (k + 1) * 1024 + ((ak * 2 + bk) << 8);
#pragma unroll
      for (int r = 0; r < 16; r++) u[r] = 0.f;
#pragma unroll
      for (int l = 0; l < 16; l++) {
        const float4 ca = *(const float4*)(ck + l * 16);
        const float4 cb = *(const float4*)(ck + l * 16 + 4);
        const float4 cc = *(const float4*)(ck + l * 16 + 8);
        const float4 cd = *(const float4*)(ck + l * 16 + 12);
        const float tv = t[l];
        u[0] += tv * ca.x;  u[1] += tv * ca.y;  u[2] += tv * ca.z;  u[3] += tv * ca.w;
        u[4] += tv * cb.x;  u[5] += tv * cb.y;  u[6] += tv * cb.z;  u[7] += tv * cb.w;
        u[8] += tv * cc.x;  u[9] += tv * cc.y;  u[10] += tv * cc.z; u[11] += tv * cc.w;
        u[12] += tv * cd.x; u[13] += tv * cd.y; u[14] += tv * cd.z; u[15] += tv * cd.w;
      }
#pragma unroll
      for (int r = 0; r < 16; r++) t[r] = u[r];
    }
    float4* dst = (float4*)(L4 + (size_t)idx * 16);
#pragma unroll
    for (int j = 0; j < 4; j++)
      dst[j] = make_float4(t[4 * j], t[4 * j + 1], t[4 * j + 2], t[4 * j + 3]);
  } else {
    for (int i = tid; i < 1024; i += 256) {
      sC[i]        = p5[i];
      sC[1024 + i] = p6[i];
      sC[2048 + i] = p7[i];
    }
    for (int i = tid; i < 64; i += 256) sC[3072 + i] = p8[i];
    __syncthreads();
    const int AR = tid >> 4, BR = tid & 15;
    const int a5 = AR >> 3, a6 = (AR >> 2) & 1, a7 = (AR >> 1) & 1, a8 = AR & 1;
    const int b5 = BR >> 3, b6 = (BR >> 2) & 1, b7 = (BR >> 1) & 1, b8 = BR & 1;
    float t[16], u[16];
    {
      const float4* c8 = (const float4*)(sC + 3072 + (a8 * 2 + b8) * 16);
      float4 a = c8[0], b = c8[1], c = c8[2], d = c8[3];
      t[0] = a.x; t[1] = a.y; t[2] = a.z; t[3] = a.w;
      t[4] = b.x; t[5] = b.y; t[6] = b.z; t[7] = b.w;
      t[8] = c.x; t[9] = c.y; t[10] = c.z; t[11] = c.w;
      t[12] = d.x; t[13] = d.y; t[14] = d.z; t[15] = d.w;
    }
    // stage 7 (bond-swapped): u[y] = sum_z t[z] * p7[(a7,b7)][z][y]
    {
      const float* c7 = sC + 2048 + ((a7 * 2 + b7) << 8);
#pragma unroll
      for (int r = 0; r < 16; r++) u[r] = 0.f;
#pragma unroll
      for (int z = 0; z < 16; z++) {
        const float4 ca = *(const float4*)(c7 + z * 16);
        const float4 cb = *(const float4*)(c7 + z * 16 + 4);
        const float4 cc = *(const float4*)(c7 + z * 16 + 8);
        const float4 cd = *(const float4*)(c7 + z * 16 + 12);
        const float tv = t[z];
        u[0] += tv * ca.x;  u[1] += tv * ca.y;  u[2] += tv * ca.z;  u[3] += tv * ca.w;
        u[4] += tv * cb.x;  u[5] += tv * cb.y;  u[6] += tv * cb.z;  u[7] += tv * cb.w;
        u[8] += tv * cc.x;  u[9] += tv * cc.y;  u[10] += tv * cc.z; u[11] += tv * cc.w;
        u[12] += tv * cd.x; u[13] += tv * cd.y; u[14] += tv * cd.z; u[15] += tv * cd.w;
      }
#pragma unroll
      for (int r = 0; r < 16; r++) t[r] = u[r];
    }
    // stage 6: u[rl] = sum_rk t[rk] * p6[(a6,b6)][rl][rk]  (dot along fast axis)
    {
      const float* c6 = sC + 1024 + ((a6 * 2 + b6) << 8);
#pragma unroll
      for (int rl = 0; rl < 16; rl++) {
        const float4 ca = *(const float4*)(c6 + rl * 16);
        const float4 cb = *(const float4*)(c6 + rl * 16 + 4);
        const float4 cc = *(const float4*)(c6 + rl * 16 + 8);
        const float4 cd = *(const float4*)(c6 + rl * 16 + 12);
        float s = 0.f;
        s += t[0] * ca.x;  s += t[1] * ca.y;  s += t[2] * ca.z;  s += t[3] * ca.w;
        s += t[4] * cb.x;  s += t[5] * cb.y;  s += t[6] * cb.z;  s += t[7] * cb.w;
        s += t[8] * cc.x;  s += t[9] * cc.y;  s += t[10] * cc.z; s += t[11] * cc.w;
        s += t[12] * cd.x; s += t[13] * cd.y; s += t[14] * cd.z; s += t[15] * cd.w;
        u[rl] = s;
      }
#pragma unroll
      for (int r = 0; r < 16; r++) t[r] = u[r];
    }
    // stage 5: R[tid*16+rl] = sum_rk t[rk] * p5[(a5,b5)][rl][rk]
    {
      const float* c5 = sC + ((a5 * 2 + b5) << 8);
#pragma unroll
      for (int rl = 0; rl < 16; rl++) {
        const float4 ca = *(const float4*)(c5 + rl * 16);
        const float4 cb = *(const float4*)(c5 + rl * 16 + 4);
        const float4 cc = *(const float4*)(c5 + rl * 16 + 8);
        const float4 cd = *(const float4*)(c5 + rl * 16 + 12);
        float s = 0.f;
        s += t[0] * ca.x;  s += t[1] * ca.y;  s += t[2] * ca.z;  s += t[3] * ca.w;
        s += t[4] * cb.x;  s += t[5] * cb.y;  s += t[6] * cb.z;  s += t[7] * cb.w;
        s += t[8] * cc.x;  s += t[9] * cc.y;  s += t[10] * cc.z; s += t[11] * cc.w;
        s += t[12] * cd.x; s += t[13] * cd.y; s += t[14] * cd.z; s += t[15] * cd.w;
        R[tid * 16 + rl] = s;
      }
    }
  }
}

// ---------------------------------------------------------------------------
// prep: fused merge (blocks 0..2047) + cast_x (blocks 2048..10239).
// ---------------------------------------------------------------------------
__global__ __launch_bounds__(256) void prep_kernel(const float* __restrict__ L4,
                                                   const float* __restrict__ R,
                                                   u16* __restrict__ Wt,
                                                   const float* __restrict__ x,
                                                   u16* __restrict__ xb) {
  if (blockIdx.x < 2048) {
    // merge: Wt[n][k] = sum_r L4[k>>4][n>>4][r] * R[k&15][n&15][r], bf16.
    int t = blockIdx.x * 256 + threadIdx.x;
    int e = t * 8;
    int Af = e & 2047;                        // k index (8-aligned)
    int Bf = e >> 11;                         // n index
    const float* lrow = L4 + ((Af >> 4) * 128 + (Bf >> 4)) * 16;
    float lv[16];
#pragma unroll
    for (int r = 0; r < 16; r++) lv[r] = lrow[r];
    const float* rbase = R + (Bf & 15) * 16;  // + (Af&15)*256
    u16x8 o;
#pragma unroll
    for (int j = 0; j < 8; j++) {
      const float* rrow = rbase + ((Af + j) & 15) * 256;
      float s = 0.f;
#pragma unroll
      for (int r = 0; r < 16; r++) s += lv[r] * rrow[r];
      o[j] = f2bf(s);
    }
    *(u16x8*)(Wt + (size_t)Bf * 2048 + Af) = o;
  } else {
    // cast_x: fp32 -> bf16, 8 elements per thread.
    size_t i = ((size_t)(blockIdx.x - 2048) * 256 + threadIdx.x) * 8;
    float4 u = *(const float4*)(x + i);
    float4 v = *(const float4*)(x + i + 4);
    u16x8 o;
    o[0] = f2bf(u.x); o[1] = f2bf(u.y); o[2] = f2bf(u.z); o[3] = f2bf(u.w);
    o[4] = f2bf(v.x); o[5] = f2bf(v.y); o[6] = f2bf(v.z); o[7] = f2bf(v.w);
    *(u16x8*)(xb + i) = o;
  }
}

// ---------------------------------------------------------------------------
// gemm (unchanged from R4, 80.2 us / MfmaUtil ~35%): 256x256 tile, BK=64,
// 8 waves, 1 block/CU. k-slice phases, reads one phase ahead with LGKM(6);
// single stage burst per tile gated by vmcnt(0)+barrier at p3.
// Swizzle: LDS(row r, oct p) = global(r, p^(r&7)); staging lane l fetches
// global octet (l&7)^(l>>3); read octet (2ks+hl)^(r&7).
// C/D: col=lane&31, row=(reg&3)+8*(reg>>2)+4*hl.
// ---------------------------------------------------------------------------
#define SB0() __builtin_amdgcn_sched_barrier(0)
#define LGKM(n) asm volatile("s_waitcnt lgkmcnt(" #n ")" ::: "memory")
#define VMCW(n) asm volatile("s_waitcnt vmcnt(" #n ")" ::: "memory")
#define BAR() asm volatile("s_barrier" ::: "memory")

#define STAGE1(Sbase, dsto, gp, uoff)                                          \
  __builtin_amdgcn_global_load_lds(                                            \
      (const __attribute__((address_space(1))) void*)((gp) + (uoff) + pl),     \
      (__attribute__((address_space(3))) void*)((Sbase) + (dsto) + ldst), 16, 0, 0)

#define STAGE_A(h, dsto, gk)                                                   \
  STAGE1(As, (dsto), A, uA + ((h)*128) * 2048 + (gk));                         \
  STAGE1(As, (dsto) + 4096, A, uA + ((h)*128 + 64) * 2048 + (gk))

#define STAGE_B(h, dsto, gk)                                                   \
  STAGE1(Bs, (dsto), B, uB + ((h)*128) * 2048 + (gk));                         \
  STAGE1(Bs, (dsto) + 4096, B, uB + ((h)*128 + 64) * 2048 + (gk))

// read the 6 frags (4 A + 2 B) of one k-slice into a register set
#define READ_KS(aS, bS, ks, base)                                              \
  _Pragma("unroll") for (int ah_ = 0; ah_ < 2; ah_++)                          \
      _Pragma("unroll") for (int m_ = 0; m_ < 2; m_++)                         \
          aS[ah_][m_] = *(const bf16x8*)(As + (base) + ah_ * 8192 + rbA +      \
                                         m_ * 2048 + ((((ks)*2 + hl) ^ key) * 8)); \
  _Pragma("unroll") for (int bh_ = 0; bh_ < 2; bh_++)                          \
      bS[bh_] = *(const bf16x8*)(Bs + (base) + bh_ * 8192 + rbB +              \
                                 ((((ks)*2 + hl) ^ key) * 8))

// 8 independent MFMAs: all (ah, bh, m) fragments at one k-slice
#define MFMA_KS(aS, bS)                                                        \
  acc[0][0][0] = __builtin_amdgcn_mfma_f32_32x32x16_bf16(aS[0][0], bS[0], acc[0][0][0], 0, 0, 0); \
  acc[1][0][0] = __builtin_amdgcn_mfma_f32_32x32x16_bf16(aS[1][0], bS[0], acc[1][0][0], 0, 0, 0); \
  acc[0][1][0] = __builtin_amdgcn_mfma_f32_32x32x16_bf16(aS[0][0], bS[1], acc[0][1][0], 0, 0, 0); \
  acc[1][1][0] = __builtin_amdgcn_mfma_f32_32x32x16_bf16(aS[1][0], bS[1], acc[1][1][0], 0, 0, 0); \
  acc[0][0][1] = __builtin_amdgcn_mfma_f32_32x32x16_bf16(aS[0][1], bS[0], acc[0][0][1], 0, 0, 0); \
  acc[1][0][1] = __builtin_amdgcn_mfma_f32_32x32x16_bf16(aS[1][1], bS[0], acc[1][0][1], 0, 0, 0); \
  acc[0][1][1] = __builtin_amdgcn_mfma_f32_32x32x16_bf16(aS[0][1], bS[1], acc[0][1][1], 0, 0, 0); \
  acc[1][1][1] = __builtin_amdgcn_mfma_f32_32x32x16_bf16(aS[1][1], bS[1], acc[1][1][1], 0, 0, 0)

__global__ __launch_bounds__(512, 2) void gemm_kernel(const u16* __restrict__ A,
                                                      const u16* __restrict__ B,
                                                      float* __restrict__ C) {
  __shared__ alignas(128) u16 As[4 * 8192];   // 64 KiB: 2 parity x 2 half
  __shared__ alignas(128) u16 Bs[4 * 8192];   // 64 KiB
  const int tid = threadIdx.x;
  const int lane = tid & 63;
  const int w = tid >> 6;        // wave 0..7
  const int wr = w >> 2;         // M split (0..1)
  const int wc = w & 3;          // N split (0..3)
  const int r32 = lane & 31;
  const int hl = lane >> 5;

  // T1: XCD x <- flat%8 gets by in [4x,4x+4), all 8 bx.
  const int F = blockIdx.x + (blockIdx.y << 3);
  const int li = F >> 3;
  const int m0 = ((F & 7) * 4 + (li >> 3)) << 8;
  const int n0 = (li & 7) << 8;

  // staging: lane l -> LDS linear l*16B (row l>>3, oct l&7); global octet
  // soct = (l&7)^(l>>3).
  const int srow = lane >> 3;
  const int soct = (lane & 7) ^ srow;
  const int uA = m0 * 2048;
  const int uB = n0 * 2048;
  const int pl = (w * 8 + srow) * 2048 + soct * 8;
  const int ldst = w * 512;           // u16: wave's 8 stage rows within slot

  const int key = r32 & 7;            // read-side swizzle key
  const int rbA = (wr * 64 + r32) * 64;
  const int rbB = (wc * 32 + r32) * 64;

  f32x16 acc[2][2][2] = {};
  bf16x8 a0_[2][2], b0_[2];   // even-ks register set
  bf16x8 a1_[2][2], b1_[2];   // odd-ks register set

  // Prologue: stage tile 0 (parity 0), drain, read ks0 -> S0 (drains at
  // p0's LGKM(6)).
  STAGE_A(0, 0, 0); STAGE_A(1, 8192, 0);
  STAGE_B(0, 0, 0); STAGE_B(1, 8192, 0);
  VMCW(0);
  BAR();
  SB0();
  READ_KS(a0_, b0_, 0, 0);
  SB0();

#pragma unroll 1
  for (int t = 0; t < 32; t++) {
    const int pav = (t & 1) << 14;    // current-parity slot base (u16)
    const int pnv = 16384 - pav;      // next-parity slot base
    const int k1 = (t < 31 ? t + 1 : 31) * 64;
    // ---- p0: stage tile t+1 (4 half-tiles) -> pnv; read ks1; MFMA ks0
    STAGE_A(0, pnv, k1); STAGE_A(1, pnv + 8192, k1);
    STAGE_B(0, pnv, k1); STAGE_B(1, pnv + 8192, k1);
    SB0();
    READ_KS(a1_, b1_, 1, pav);
    SB0();
    LGKM(6); SB0();                   // ks0 done (issued last phase); ks1 in flight
    __builtin_amdgcn_s_setprio(1);
    MFMA_KS(a0_, b0_);
    __builtin_amdgcn_s_setprio(0);
    SB0();
    // ---- p1: read ks2 -> S0; MFMA ks1
    READ_KS(a0_, b0_, 2, pav);
    SB0();
    LGKM(6); SB0();
    __builtin_amdgcn_s_setprio(1);
    MFMA_KS(a1_, b1_);
    __builtin_amdgcn_s_setprio(0);
    SB0();
    // ---- p2: read ks3 -> S1; MFMA ks2
    READ_KS(a1_, b1_, 3, pav);
    SB0();
    LGKM(6); SB0();
    __builtin_amdgcn_s_setprio(1);
    MFMA_KS(a0_, b0_);
    __builtin_amdgcn_s_setprio(0);
    SB0();
    // ---- p3: gate tile t+1 residency; read ks0(t+1) from pnv; MFMA ks3
    VMCW(0);
    BAR();
    SB0();
    READ_KS(a0_, b0_, 0, pnv);
    SB0();
    LGKM(6); SB0();                   // ks3 done; ks0(t+1) in flight
    __builtin_amdgcn_s_setprio(1);
    MFMA_KS(a1_, b1_);
    __builtin_amdgcn_s_setprio(0);
    SB0();
    BAR();
    SB0();
  }

  // drain the tail's dead ks0 reads and any DMA before LDS dealloc
  LGKM(0);
  VMCW(0);

#pragma unroll
  for (int ah = 0; ah < 2; ah++)
#pragma unroll
    for (int bh = 0; bh < 2; bh++)
#pragma unroll
      for (int m = 0; m < 2; m++) {
        size_t cbase = (size_t)(m0 + ah * 128 + wr * 64 + m * 32 + 4 * hl) * 2048 +
                       (n0 + bh * 128 + wc * 32 + r32);
#pragma unroll
        for (int reg = 0; reg < 16; reg++) {
          int row = (reg & 3) + 8 * (reg >> 2);   // +4*hl folded into cbase
          __builtin_nontemporal_store(acc[ah][bh][m][reg], C + cbase + (size_t)row * 2048);
        }
      }
}

extern "C" void kernel_launch(void* const* d_in, const int* in_sizes, int n_in,
                              void* d_out, int out_size, void* d_ws, size_t ws_size,
                              hipStream_t stream) {
  const float* x = (const float*)d_in[0];
  const float* p0 = (const float*)d_in[1];
  const float* p1 = (const float*)d_in[2];
  const float* p2 = (const float*)d_in[3];
  const float* p3 = (const float*)d_in[4];
  const float* p4 = (const float*)d_in[5];
  const float* p5 = (const float*)d_in[6];
  const float* p6 = (const float*)d_in[7];
  const float* p7 = (const float*)d_in[8];
  const float* p8 = (const float*)d_in[9];
  char* ws = (char*)d_ws;
  // ws layout (bytes): xbf 33554432 | Wt 8388608 | L4 1048576 | R 16384
  u16* xbf = (u16*)ws;
  u16* Wt = (u16*)(ws + 33554432);
  float* L4 = (float*)(ws + 41943040);
  float* R = (float*)(ws + 42991616);

  build_lr_kernel<<<65, 256, 0, stream>>>(p0, p1, p2, p3, p4, p5, p6, p7, p8, L4, R);
  prep_kernel<<<10240, 256, 0, stream>>>(L4, R, Wt, x, xbf);
  gemm_kernel<<<dim3(8, 32), 512, 0, stream>>>(xbf, Wt, (float*)d_out);
}